// Round 6
// baseline (1433.728 us; speedup 1.0000x reference)
//
#include <hip/hip_runtime.h>

typedef unsigned short u16;
typedef __attribute__((ext_vector_type(8))) short s16x8;
typedef __attribute__((ext_vector_type(4))) float f32x4;

__device__ __forceinline__ float bf2f(u16 u) {
    union { unsigned i; float f; } v; v.i = (unsigned)u << 16; return v.f;
}
__device__ __forceinline__ u16 f2bf(float f) {
    union { float f; unsigned i; } v; v.f = f;
    unsigned r = v.i + 0x7fffu + ((v.i >> 16) & 1u);
    return (u16)(r >> 16);
}
__device__ __forceinline__ unsigned fbits(float f) {
    union { float f; unsigned i; } v; v.f = f; return v.i;
}
__device__ __forceinline__ f32x4 mfma16(s16x8 a, s16x8 b, f32x4 c) {
    return __builtin_amdgcn_mfma_f32_16x16x32_bf16(a, b, c, 0, 0, 0);
}

// ---------------------------------------------------------------------------
// fp32 -> bf16 conversion
// ---------------------------------------------------------------------------
__global__ __launch_bounds__(256)
void cvt_kernel(const float* __restrict__ src, u16* __restrict__ dst, int n)
{
    for (int i = blockIdx.x * 256 + threadIdx.x; i < n; i += gridDim.x * 256)
        dst[i] = f2bf(src[i]);
}

// ---------------------------------------------------------------------------
// cls rows: h[b, s<12, :] = cls[s] + pos[s]
// ---------------------------------------------------------------------------
__global__ __launch_bounds__(256)
void embed_cls_kernel(const float* __restrict__ cls, const float* __restrict__ pos,
                      float* __restrict__ h32, u16* __restrict__ h16)
{
    int i = blockIdx.x * 256 + threadIdx.x;           // < 128*12*128
    int e = i & 127, s = (i >> 7) % 12, b = i / (12 * 128);
    float v = cls[s * 128 + e] + pos[s * 128 + e];
    size_t o = ((size_t)b * 264 + s) * 128 + e;
    h32[o] = v; h16[o] = f2bf(v);
}

// ---------------------------------------------------------------------------
// Conv-embed via MFMA: rows = (b,l) flat [32256], K=96, N=128.
// ---------------------------------------------------------------------------
__global__ __launch_bounds__(256)
void embed_mfma(const u16* __restrict__ x16, const u16* __restrict__ cw16,
                const float* __restrict__ cb, const float* __restrict__ pos,
                const float* __restrict__ ttab, const float* __restrict__ stab,
                const int* __restrict__ tidx, const int* __restrict__ sidx,
                float* __restrict__ h32, u16* __restrict__ h16)
{
    const int t = threadIdx.x;
    const int wave = t >> 6, lane = t & 63;
    const int quad = lane >> 4, l16 = lane & 15;
    const int n0 = wave * 32;

    s16x8 wf[2][3];
    float bv[2];
    #pragma unroll
    for (int nt = 0; nt < 2; ++nt) {
        bv[nt] = cb[n0 + nt * 16 + l16];
        #pragma unroll
        for (int ks = 0; ks < 3; ++ks)
            wf[nt][ks] = *(const s16x8*)&cw16[(n0 + nt * 16 + l16) * 96 + ks * 32 + quad * 8];
    }
    #pragma unroll
    for (int tt = 0; tt < 4; ++tt) {
        const int m0 = (blockIdx.x * 4 + tt) * 16;
        s16x8 af[3];
        #pragma unroll
        for (int ks = 0; ks < 3; ++ks)
            af[ks] = *(const s16x8*)&x16[(size_t)(m0 + l16) * 96 + ks * 32 + quad * 8];
        f32x4 a0 = (f32x4){0.f,0.f,0.f,0.f}, a1 = (f32x4){0.f,0.f,0.f,0.f};
        #pragma unroll
        for (int ks = 0; ks < 3; ++ks) {
            a0 = mfma16(af[ks], wf[0][ks], a0);
            a1 = mfma16(af[ks], wf[1][ks], a1);
        }
        #pragma unroll
        for (int r = 0; r < 4; ++r) {
            int row = m0 + quad * 4 + r;
            int b = row / 252, l = row - b * 252;
            int ti = tidx[row], si = sidx[row];
            size_t tok = (size_t)b * 264 + 12 + l;
            #pragma unroll
            for (int nt = 0; nt < 2; ++nt) {
                int col = n0 + nt * 16 + l16;
                float v = (nt ? a1[r] : a0[r]) + bv[nt]
                        + pos[(12 + l) * 128 + col]
                        + ttab[ti * 128 + col] + stab[si * 128 + col];
                h32[tok * 128 + col] = v;
                h16[tok * 128 + col] = f2bf(v);
            }
        }
    }
}

// ---------------------------------------------------------------------------
// C[M,N] = act(A[M,128] @ W[N,128]^T + bias). 128x128 tile, 4 waves (2x2 of
// 64x64). XOR-swizzled padless LDS (64 KB). Staging: 8x256 iters cover the
// FULL 128 rows x 16 chunks (R5 bug: only half was written).
// QSCALE: multiply output by 0.25*log2(e) when blockIdx.y==0 (Q cols of qkv).
// ---------------------------------------------------------------------------
template<bool RELU, bool QSCALE>
__global__ __launch_bounds__(256)
void gemm_bias(const u16* __restrict__ A, const u16* __restrict__ W,
               const float* __restrict__ bias, u16* __restrict__ C, int N)
{
    __shared__ alignas(16) u16 As[128 * 128];
    __shared__ alignas(16) u16 Ws[128 * 128];
    const int m0 = blockIdx.x * 128;
    const int n0 = blockIdx.y * 128;
    const int t = threadIdx.x;
    const int wave = t >> 6, lane = t & 63;
    const int quad = lane >> 4, l16 = lane & 15;
    const int wm = (wave & 1) * 64, wn = (wave >> 1) * 64;

    #pragma unroll
    for (int i = 0; i < 8; ++i) {
        int id = i * 256 + t;
        int row = id >> 4, c = id & 15, sw = c ^ (row & 15);
        *(uint4*)&As[row * 128 + sw * 8] = *(const uint4*)&A[(size_t)(m0 + row) * 128 + c * 8];
        *(uint4*)&Ws[row * 128 + sw * 8] = *(const uint4*)&W[(size_t)(n0 + row) * 128 + c * 8];
    }
    __syncthreads();

    f32x4 acc[4][4];
    #pragma unroll
    for (int i = 0; i < 4; ++i)
        #pragma unroll
        for (int j = 0; j < 4; ++j) acc[i][j] = (f32x4){0.f, 0.f, 0.f, 0.f};

    #pragma unroll
    for (int ks = 0; ks < 4; ++ks) {
        const int sw = (ks * 4 + quad) ^ l16;
        s16x8 af[4], bf[4];
        #pragma unroll
        for (int i = 0; i < 4; ++i) {
            af[i] = *(const s16x8*)&As[(wm + i * 16 + l16) * 128 + sw * 8];
            bf[i] = *(const s16x8*)&Ws[(wn + i * 16 + l16) * 128 + sw * 8];
        }
        #pragma unroll
        for (int mi = 0; mi < 4; ++mi)
            #pragma unroll
            for (int ni = 0; ni < 4; ++ni)
                acc[mi][ni] = mfma16(af[mi], bf[ni], acc[mi][ni]);
    }
    #pragma unroll
    for (int ni = 0; ni < 4; ++ni) {
        int col = n0 + wn + ni * 16 + l16;
        float bv = bias[col];
        #pragma unroll
        for (int mi = 0; mi < 4; ++mi) {
            #pragma unroll
            for (int r = 0; r < 4; ++r) {
                int row = m0 + wm + mi * 16 + quad * 4 + r;
                float v = acc[mi][ni][r] + bv;
                if (RELU) v = fmaxf(v, 0.f);
                if (QSCALE && blockIdx.y == 0) v *= 0.360673760222241f; // 0.25*log2(e)
                C[(size_t)row * N + col] = f2bf(v);
            }
        }
    }
}

// ---------------------------------------------------------------------------
// Fused: y = LN(A[M,K] @ W[128,K]^T + bias + resid). 128-row block, 4 waves;
// wave owns 32 full rows (2 m-tiles x 8 n-tiles) -> in-wave LN.
// XOR-swizzled padless LDS; full-tile staging (8x256 iters per buffer).
// ---------------------------------------------------------------------------
template<int K>
__global__ __launch_bounds__(256)
void gemm_ln(const u16* __restrict__ A, const u16* __restrict__ W,
             const float* __restrict__ bias, const float* resid,
             const float* __restrict__ g, const float* __restrict__ be,
             float* o32, u16* o16)
{
    __shared__ alignas(16) u16 As[128 * 128];
    __shared__ alignas(16) u16 Ws[128 * 128];
    const int m0 = blockIdx.x * 128;
    const int t = threadIdx.x;
    const int wave = t >> 6, lane = t & 63;
    const int quad = lane >> 4, l16 = lane & 15;

    f32x4 acc[2][8];
    #pragma unroll
    for (int i = 0; i < 2; ++i)
        #pragma unroll
        for (int j = 0; j < 8; ++j) acc[i][j] = (f32x4){0.f, 0.f, 0.f, 0.f};

    for (int kc = 0; kc < K; kc += 128) {
        __syncthreads();
        #pragma unroll
        for (int i = 0; i < 8; ++i) {
            int id = i * 256 + t;
            int row = id >> 4, c = id & 15, sw = c ^ (row & 15);
            *(uint4*)&As[row * 128 + sw * 8] = *(const uint4*)&A[(size_t)(m0 + row) * K + kc + c * 8];
            *(uint4*)&Ws[row * 128 + sw * 8] = *(const uint4*)&W[(size_t)row * K + kc + c * 8];
        }
        __syncthreads();
        #pragma unroll
        for (int ks = 0; ks < 4; ++ks) {
            const int sw = (ks * 4 + quad) ^ l16;
            s16x8 a0 = *(const s16x8*)&As[(wave * 32 + l16) * 128 + sw * 8];
            s16x8 a1 = *(const s16x8*)&As[(wave * 32 + 16 + l16) * 128 + sw * 8];
            #pragma unroll
            for (int nt = 0; nt < 8; ++nt) {
                s16x8 b = *(const s16x8*)&Ws[(nt * 16 + l16) * 128 + sw * 8];
                acc[0][nt] = mfma16(a0, b, acc[0][nt]);
                acc[1][nt] = mfma16(a1, b, acc[1][nt]);
            }
        }
    }
    #pragma unroll
    for (int mi = 0; mi < 2; ++mi) {
        #pragma unroll
        for (int nt = 0; nt < 8; ++nt) {
            int col = nt * 16 + l16;
            float bv = bias[col];
            #pragma unroll
            for (int r = 0; r < 4; ++r) {
                int row = m0 + wave * 32 + mi * 16 + quad * 4 + r;
                acc[mi][nt][r] += bv + resid[(size_t)row * 128 + col];
            }
        }
        float sm[4], sq[4];
        #pragma unroll
        for (int r = 0; r < 4; ++r) {
            float s = 0.f, q = 0.f;
            #pragma unroll
            for (int nt = 0; nt < 8; ++nt) { float v = acc[mi][nt][r]; s += v; q += v * v; }
            sm[r] = s; sq[r] = q;
        }
        #pragma unroll
        for (int mk = 1; mk < 16; mk <<= 1) {
            #pragma unroll
            for (int r = 0; r < 4; ++r) {
                sm[r] += __shfl_xor(sm[r], mk, 64);
                sq[r] += __shfl_xor(sq[r], mk, 64);
            }
        }
        #pragma unroll
        for (int r = 0; r < 4; ++r) {
            float mean = sm[r] * (1.f / 128.f);
            float var = sq[r] * (1.f / 128.f) - mean * mean;
            float rstd = rsqrtf(var + 1e-5f);
            int row = m0 + wave * 32 + mi * 16 + quad * 4 + r;
            #pragma unroll
            for (int nt = 0; nt < 8; ++nt) {
                int col = nt * 16 + l16;
                float y = (acc[mi][nt][r] - mean) * rstd * g[col] + be[col];
                o32[(size_t)row * 128 + col] = y;
                o16[(size_t)row * 128 + col] = f2bf(y);
            }
        }
    }
}

// ---------------------------------------------------------------------------
// Attention v3: transpose-free + VALU diet. Q pre-scaled by 0.25*log2(e) in
// the qkv GEMM, exp via raw v_exp_f32 (exp2), P packed by v_perm truncation,
// 1/l normalization deferred to the 4-element output.
// ---------------------------------------------------------------------------
__global__ __launch_bounds__(256)
void attn_kernel(const u16* __restrict__ qkv, u16* __restrict__ ctx)
{
    const int STR = 296;  // VT: [d=16][key padded], keys 264..295 zeroed
    const int KLD = 24;   // Ks: [key=272][d=16 pad 24]
    __shared__ alignas(16) u16 VT[16 * STR];
    __shared__ alignas(16) u16 Ks[272 * KLD];
    const int b = blockIdx.x >> 3, h = blockIdx.x & 7;
    const size_t base = (size_t)b * 264 * 384;
    const int t = threadIdx.x;
    const int wave = t >> 6, lane = t & 63;
    const int quad = lane >> 4, l16 = lane & 15;
    const int hq = h * 16;

    for (int i = t; i < 264 * 2; i += 256) {
        int key = i >> 1, dq = (i & 1) * 8;
        *(uint4*)&Ks[key * KLD + dq] =
            *(const uint4*)&qkv[base + (size_t)key * 384 + 128 + hq + dq];
    }
    for (int i = t; i < 264 * 16; i += 256) {
        int s = i >> 4, d = i & 15;
        VT[d * STR + s] = qkv[base + (size_t)s * 384 + 256 + hq + d];
    }
    for (int i = t; i < 16 * 32; i += 256) {
        int d = i >> 5, c = 264 + (i & 31);
        VT[d * STR + c] = 0;
    }
    __syncthreads();

    for (int qt = wave; qt < 17; qt += 4) {
        const int q0 = qt * 16;
        s16x8 qf = (s16x8){0, 0, 0, 0, 0, 0, 0, 0};
        {
            int qrow = q0 + l16;
            if (quad < 2 && qrow < 264)
                qf = *(const s16x8*)&qkv[base + (size_t)qrow * 384 + hq + quad * 8];
        }
        f32x4 sc[17];
        #pragma unroll
        for (int kt = 0; kt < 17; ++kt) {
            s16x8 kf = (s16x8){0, 0, 0, 0, 0, 0, 0, 0};
            if (quad < 2)
                kf = *(const s16x8*)&Ks[(kt * 16 + l16) * KLD + quad * 8];
            f32x4 z = (f32x4){0.f, 0.f, 0.f, 0.f};
            sc[kt] = mfma16(kf, qf, z);
        }
        // softmax in log2 domain (Q pre-scaled); key = kt*16 + quad*4 + r
        float mx = -1e30f;
        #pragma unroll
        for (int kt = 0; kt < 17; ++kt) {
            #pragma unroll
            for (int r = 0; r < 4; ++r) {
                float s = sc[kt][r];
                if (kt == 16 && quad >= 2) s = -1e30f;   // keys >= 264
                sc[kt][r] = s;
                mx = fmaxf(mx, s);
            }
        }
        mx = fmaxf(mx, __shfl_xor(mx, 16, 64));
        mx = fmaxf(mx, __shfl_xor(mx, 32, 64));
        float ls = 0.f;
        #pragma unroll
        for (int kt = 0; kt < 17; ++kt) {
            #pragma unroll
            for (int r = 0; r < 4; ++r) {
                float e = __builtin_amdgcn_exp2f(sc[kt][r] - mx);
                sc[kt][r] = e;
                ls += e;
            }
        }
        ls += __shfl_xor(ls, 16, 64);
        ls += __shfl_xor(ls, 32, 64);
        float rinv = 1.f / ls;
        float rinvT[4];
        #pragma unroll
        for (int r = 0; r < 4; ++r) rinvT[r] = __shfl(rinv, quad * 4 + r, 64);

        // PV: P packed from sc regs via v_perm hi16 truncation
        f32x4 oa = (f32x4){0.f, 0.f, 0.f, 0.f};
        #pragma unroll
        for (int c = 0; c < 9; ++c) {
            const int kt0 = 2 * c, kt1 = 2 * c + 1;
            union { s16x8 v; uint4 w; } pk;
            pk.w.x = __builtin_amdgcn_perm(fbits(sc[kt0][1]), fbits(sc[kt0][0]), 0x07060302u);
            pk.w.y = __builtin_amdgcn_perm(fbits(sc[kt0][3]), fbits(sc[kt0][2]), 0x07060302u);
            if (c == 8) { pk.w.z = 0; pk.w.w = 0; }
            else {
                pk.w.z = __builtin_amdgcn_perm(fbits(sc[kt1][1]), fbits(sc[kt1][0]), 0x07060302u);
                pk.w.w = __builtin_amdgcn_perm(fbits(sc[kt1][3]), fbits(sc[kt1][2]), 0x07060302u);
            }
            union { s16x8 v; uint2 h2[2]; } vt;
            vt.h2[0] = *(const uint2*)&VT[l16 * STR + kt0 * 16 + quad * 4];
            vt.h2[1] = *(const uint2*)&VT[l16 * STR + kt1 * 16 + quad * 4];
            oa = mfma16(pk.v, vt.v, oa);
        }
        #pragma unroll
        for (int r = 0; r < 4; ++r) {
            int row = q0 + quad * 4 + r;
            if (row < 264)
                ctx[((size_t)b * 264 + row) * 128 + hq + l16] = f2bf(oa[r] * rinvT[r]);
        }
    }
}

// ---------------------------------------------------------------------------
extern "C" void kernel_launch(void* const* d_in, const int* in_sizes, int n_in,
                              void* d_out, int out_size, void* d_ws, size_t ws_size,
                              hipStream_t stream)
{
    (void)in_sizes; (void)n_in; (void)out_size; (void)ws_size;
    const float* x    = (const float*)d_in[0];
    const int*   tidx = (const int*)d_in[1];
    const int*   sidx = (const int*)d_in[2];
    const float* cw   = (const float*)d_in[3];
    const float* cb   = (const float*)d_in[4];
    const float* pos  = (const float*)d_in[5];
    const float* ttab = (const float*)d_in[6];
    const float* stab = (const float*)d_in[7];
    const float* cls  = (const float*)d_in[8];
    const float* Wqkv = (const float*)d_in[9];
    const float* bqkv = (const float*)d_in[10];
    const float* Wo   = (const float*)d_in[11];
    const float* bo   = (const float*)d_in[12];
    const float* W1   = (const float*)d_in[13];
    const float* b1   = (const float*)d_in[14];
    const float* W2   = (const float*)d_in[15];
    const float* b2   = (const float*)d_in[16];
    const float* g1   = (const float*)d_in[17];
    const float* be1  = (const float*)d_in[18];
    const float* g2   = (const float*)d_in[19];
    const float* be2  = (const float*)d_in[20];

    char* ws = (char*)d_ws;
    float* h32 = (float*)ws;
    u16* h16    = (u16*)(ws + 17301504);
    u16* big    = (u16*)(ws + 25952256);
    u16* ctx    = (u16*)(ws + 51904512);
    u16* wqkv16 = (u16*)(ws + 60555264);
    u16* wo16   = (u16*)(ws + 61734912);
    u16* w116   = (u16*)(ws + 62128128);
    u16* w216   = (u16*)(ws + 63700992);
    u16* x16    = big;                    // [32256, 96] bf16, free before layer 0
    u16* cw16   = ctx;                    // [128, 96]  bf16, free before layer 0

    cvt_kernel<<<512, 256, 0, stream>>>(Wqkv, wqkv16, 12 * 384 * 128);
    cvt_kernel<<<256, 256, 0, stream>>>(Wo,   wo16,   12 * 128 * 128);
    cvt_kernel<<<512, 256, 0, stream>>>(W1,   w116,   12 * 512 * 128);
    cvt_kernel<<<512, 256, 0, stream>>>(W2,   w216,   12 * 128 * 512);
    cvt_kernel<<<1024, 256, 0, stream>>>(x,   x16,    128 * 252 * 96);
    cvt_kernel<<<48, 256, 0, stream>>>(cw,    cw16,   128 * 96);
    embed_cls_kernel<<<768, 256, 0, stream>>>(cls, pos, h32, h16);
    embed_mfma<<<504, 256, 0, stream>>>(x16, cw16, cb, pos, ttab, stab, tidx, sidx, h32, h16);

    for (int l = 0; l < 12; ++l) {
        gemm_bias<false, true><<<dim3(264, 3), 256, 0, stream>>>(
            h16, wqkv16 + l * 384 * 128, bqkv + l * 384, big, 384);
        attn_kernel<<<1024, 256, 0, stream>>>(big, ctx);
        gemm_ln<128><<<264, 256, 0, stream>>>(
            ctx, wo16 + l * 128 * 128, bo + l * 128, h32, g1 + l * 128, be1 + l * 128, h32, h16);
        gemm_bias<true, false><<<dim3(264, 4), 256, 0, stream>>>(
            h16, w116 + l * 512 * 128, b1 + l * 512, big, 512);
        float* o32 = (l == 11) ? (float*)d_out : h32;
        gemm_ln<512><<<264, 256, 0, stream>>>(
            big, w216 + l * 128 * 512, b2 + l * 128, h32, g2 + l * 128, be2 + l * 128, o32, h16);
    }
}

// Round 7
// 1281.341 us; speedup vs baseline: 1.1189x; 1.1189x over previous
//
#include <hip/hip_runtime.h>

typedef unsigned short u16;
typedef __attribute__((ext_vector_type(8))) short s16x8;
typedef __attribute__((ext_vector_type(4))) float f32x4;

__device__ __forceinline__ float bf2f(u16 u) {
    union { unsigned i; float f; } v; v.i = (unsigned)u << 16; return v.f;
}
__device__ __forceinline__ u16 f2bf(float f) {
    union { float f; unsigned i; } v; v.f = f;
    unsigned r = v.i + 0x7fffu + ((v.i >> 16) & 1u);
    return (u16)(r >> 16);
}
__device__ __forceinline__ unsigned fbits(float f) {
    union { float f; unsigned i; } v; v.f = f; return v.i;
}
__device__ __forceinline__ f32x4 mfma16(s16x8 a, s16x8 b, f32x4 c) {
    return __builtin_amdgcn_mfma_f32_16x16x32_bf16(a, b, c, 0, 0, 0);
}

// ---------------------------------------------------------------------------
// fp32 -> bf16 conversion
// ---------------------------------------------------------------------------
__global__ __launch_bounds__(256)
void cvt_kernel(const float* __restrict__ src, u16* __restrict__ dst, int n)
{
    for (int i = blockIdx.x * 256 + threadIdx.x; i < n; i += gridDim.x * 256)
        dst[i] = f2bf(src[i]);
}

// ---------------------------------------------------------------------------
// cls rows: h[b, s<12, :] = cls[s] + pos[s]
// ---------------------------------------------------------------------------
__global__ __launch_bounds__(256)
void embed_cls_kernel(const float* __restrict__ cls, const float* __restrict__ pos,
                      float* __restrict__ h32, u16* __restrict__ h16)
{
    int i = blockIdx.x * 256 + threadIdx.x;           // < 128*12*128
    int e = i & 127, s = (i >> 7) % 12, b = i / (12 * 128);
    float v = cls[s * 128 + e] + pos[s * 128 + e];
    size_t o = ((size_t)b * 264 + s) * 128 + e;
    h32[o] = v; h16[o] = f2bf(v);
}

// ---------------------------------------------------------------------------
// Conv-embed via MFMA: rows = (b,l) flat [32256], K=96, N=128.
// ---------------------------------------------------------------------------
__global__ __launch_bounds__(256)
void embed_mfma(const u16* __restrict__ x16, const u16* __restrict__ cw16,
                const float* __restrict__ cb, const float* __restrict__ pos,
                const float* __restrict__ ttab, const float* __restrict__ stab,
                const int* __restrict__ tidx, const int* __restrict__ sidx,
                float* __restrict__ h32, u16* __restrict__ h16)
{
    const int t = threadIdx.x;
    const int wave = t >> 6, lane = t & 63;
    const int quad = lane >> 4, l16 = lane & 15;
    const int n0 = wave * 32;

    s16x8 wf[2][3];
    float bv[2];
    #pragma unroll
    for (int nt = 0; nt < 2; ++nt) {
        bv[nt] = cb[n0 + nt * 16 + l16];
        #pragma unroll
        for (int ks = 0; ks < 3; ++ks)
            wf[nt][ks] = *(const s16x8*)&cw16[(n0 + nt * 16 + l16) * 96 + ks * 32 + quad * 8];
    }
    #pragma unroll
    for (int tt = 0; tt < 4; ++tt) {
        const int m0 = (blockIdx.x * 4 + tt) * 16;
        s16x8 af[3];
        #pragma unroll
        for (int ks = 0; ks < 3; ++ks)
            af[ks] = *(const s16x8*)&x16[(size_t)(m0 + l16) * 96 + ks * 32 + quad * 8];
        f32x4 a0 = (f32x4){0.f,0.f,0.f,0.f}, a1 = (f32x4){0.f,0.f,0.f,0.f};
        #pragma unroll
        for (int ks = 0; ks < 3; ++ks) {
            a0 = mfma16(af[ks], wf[0][ks], a0);
            a1 = mfma16(af[ks], wf[1][ks], a1);
        }
        #pragma unroll
        for (int r = 0; r < 4; ++r) {
            int row = m0 + quad * 4 + r;
            int b = row / 252, l = row - b * 252;
            int ti = tidx[row], si = sidx[row];
            size_t tok = (size_t)b * 264 + 12 + l;
            #pragma unroll
            for (int nt = 0; nt < 2; ++nt) {
                int col = n0 + nt * 16 + l16;
                float v = (nt ? a1[r] : a0[r]) + bv[nt]
                        + pos[(12 + l) * 128 + col]
                        + ttab[ti * 128 + col] + stab[si * 128 + col];
                h32[tok * 128 + col] = v;
                h16[tok * 128 + col] = f2bf(v);
            }
        }
    }
}

// ---------------------------------------------------------------------------
// C[M,N] = act(A[M,K] @ W[N,K]^T + bias). 64x64 block tile, 4 waves, LDK=136
// (R4-proven structure: ~34 KB LDS -> 4 blocks/CU, 16 waves/CU).
// QSCALE: multiply output by 0.25*log2(e) when blockIdx.y < 2 (Q cols of qkv).
// ---------------------------------------------------------------------------
template<bool RELU, bool QSCALE>
__global__ __launch_bounds__(256)
void gemm_bias(const u16* __restrict__ A, const u16* __restrict__ W,
               const float* __restrict__ bias, u16* __restrict__ C,
               int N, int K)
{
    const int LDK = 136;
    __shared__ alignas(16) u16 As[64 * 136];
    __shared__ alignas(16) u16 Ws[64 * 136];
    const int m0 = blockIdx.x * 64;
    const int n0 = blockIdx.y * 64;
    const int t = threadIdx.x;
    const int wave = t >> 6, lane = t & 63;
    const int quad = lane >> 4, l16 = lane & 15;
    const int wm = (wave & 1) * 32, wn = (wave >> 1) * 32;

    f32x4 acc[2][2];
    #pragma unroll
    for (int i = 0; i < 2; ++i)
        #pragma unroll
        for (int j = 0; j < 2; ++j) acc[i][j] = (f32x4){0.f, 0.f, 0.f, 0.f};

    for (int kc = 0; kc < K; kc += 128) {
        __syncthreads();
        #pragma unroll
        for (int i = 0; i < 4; ++i) {
            int id = i * 256 + t;
            int row = id >> 4, c8 = (id & 15) << 3;
            *(uint4*)&As[row * LDK + c8] = *(const uint4*)&A[(size_t)(m0 + row) * K + kc + c8];
            *(uint4*)&Ws[row * LDK + c8] = *(const uint4*)&W[(size_t)(n0 + row) * K + kc + c8];
        }
        __syncthreads();
        #pragma unroll
        for (int ks = 0; ks < 4; ++ks) {
            s16x8 a0 = *(const s16x8*)&As[(wm + l16) * LDK + ks * 32 + quad * 8];
            s16x8 a1 = *(const s16x8*)&As[(wm + 16 + l16) * LDK + ks * 32 + quad * 8];
            s16x8 b0 = *(const s16x8*)&Ws[(wn + l16) * LDK + ks * 32 + quad * 8];
            s16x8 b1 = *(const s16x8*)&Ws[(wn + 16 + l16) * LDK + ks * 32 + quad * 8];
            acc[0][0] = mfma16(a0, b0, acc[0][0]);
            acc[0][1] = mfma16(a0, b1, acc[0][1]);
            acc[1][0] = mfma16(a1, b0, acc[1][0]);
            acc[1][1] = mfma16(a1, b1, acc[1][1]);
        }
    }
    #pragma unroll
    for (int ni = 0; ni < 2; ++ni) {
        int col = n0 + wn + ni * 16 + l16;
        float bv = bias[col];
        #pragma unroll
        for (int mi = 0; mi < 2; ++mi) {
            #pragma unroll
            for (int r = 0; r < 4; ++r) {
                int row = m0 + wm + mi * 16 + quad * 4 + r;
                float v = acc[mi][ni][r] + bv;
                if (RELU) v = fmaxf(v, 0.f);
                if (QSCALE && blockIdx.y < 2) v *= 0.360673760222241f; // 0.25*log2(e)
                C[(size_t)row * N + col] = f2bf(v);
            }
        }
    }
}

// ---------------------------------------------------------------------------
// Fused: y = LN(A[M,K] @ W[128,K]^T + bias + resid). 64-row block, 4 waves;
// wave owns 16 full rows -> in-wave LN. (R4-proven structure.)
// ---------------------------------------------------------------------------
template<int K>
__global__ __launch_bounds__(256)
void gemm_ln(const u16* __restrict__ A, const u16* __restrict__ W,
             const float* __restrict__ bias, const float* resid,
             const float* __restrict__ g, const float* __restrict__ be,
             float* o32, u16* o16)
{
    const int LDK = 136;
    __shared__ alignas(16) u16 As[64 * 136];
    __shared__ alignas(16) u16 Ws[128 * 136];
    const int m0 = blockIdx.x * 64;
    const int t = threadIdx.x;
    const int wave = t >> 6, lane = t & 63;
    const int quad = lane >> 4, l16 = lane & 15;
    const int wr = wave * 16;

    f32x4 acc[8];
    #pragma unroll
    for (int i = 0; i < 8; ++i) acc[i] = (f32x4){0.f, 0.f, 0.f, 0.f};

    for (int kc = 0; kc < K; kc += 128) {
        __syncthreads();
        #pragma unroll
        for (int i = 0; i < 4; ++i) {
            int id = i * 256 + t;
            int row = id >> 4, c8 = (id & 15) << 3;
            *(uint4*)&As[row * LDK + c8] = *(const uint4*)&A[(size_t)(m0 + row) * K + kc + c8];
        }
        #pragma unroll
        for (int i = 0; i < 8; ++i) {
            int id = i * 256 + t;
            int row = id >> 4, c8 = (id & 15) << 3;
            *(uint4*)&Ws[row * LDK + c8] = *(const uint4*)&W[(size_t)row * K + kc + c8];
        }
        __syncthreads();
        #pragma unroll
        for (int ks = 0; ks < 4; ++ks) {
            s16x8 a = *(const s16x8*)&As[(wr + l16) * LDK + ks * 32 + quad * 8];
            #pragma unroll
            for (int nt = 0; nt < 8; ++nt) {
                s16x8 b = *(const s16x8*)&Ws[(nt * 16 + l16) * LDK + ks * 32 + quad * 8];
                acc[nt] = mfma16(a, b, acc[nt]);
            }
        }
    }
    #pragma unroll
    for (int nt = 0; nt < 8; ++nt) {
        int col = nt * 16 + l16;
        float bv = bias[col];
        #pragma unroll
        for (int r = 0; r < 4; ++r) {
            int row = m0 + wr + quad * 4 + r;
            acc[nt][r] += bv + resid[(size_t)row * 128 + col];
        }
    }
    float sm[4], sq[4];
    #pragma unroll
    for (int r = 0; r < 4; ++r) {
        float s = 0.f, q = 0.f;
        #pragma unroll
        for (int nt = 0; nt < 8; ++nt) { float v = acc[nt][r]; s += v; q += v * v; }
        sm[r] = s; sq[r] = q;
    }
    #pragma unroll
    for (int mk = 1; mk < 16; mk <<= 1) {
        #pragma unroll
        for (int r = 0; r < 4; ++r) {
            sm[r] += __shfl_xor(sm[r], mk, 64);
            sq[r] += __shfl_xor(sq[r], mk, 64);
        }
    }
    #pragma unroll
    for (int r = 0; r < 4; ++r) {
        float mean = sm[r] * (1.f / 128.f);
        float var = sq[r] * (1.f / 128.f) - mean * mean;
        float rstd = rsqrtf(var + 1e-5f);
        int row = m0 + wr + quad * 4 + r;
        #pragma unroll
        for (int nt = 0; nt < 8; ++nt) {
            int col = nt * 16 + l16;
            float y = (acc[nt][r] - mean) * rstd * g[col] + be[col];
            o32[(size_t)row * 128 + col] = y;
            o16[(size_t)row * 128 + col] = f2bf(y);
        }
    }
}

// ---------------------------------------------------------------------------
// Attention v3: transpose-free + VALU diet. Q pre-scaled by 0.25*log2(e) in
// the qkv GEMM, exp via raw v_exp_f32 (exp2), P packed by v_perm truncation,
// 1/l normalization deferred to the 4-element output.
// ---------------------------------------------------------------------------
__global__ __launch_bounds__(256)
void attn_kernel(const u16* __restrict__ qkv, u16* __restrict__ ctx)
{
    const int STR = 296;  // VT: [d=16][key padded], keys 264..295 zeroed
    const int KLD = 24;   // Ks: [key=272][d=16 pad 24]
    __shared__ alignas(16) u16 VT[16 * STR];
    __shared__ alignas(16) u16 Ks[272 * KLD];
    const int b = blockIdx.x >> 3, h = blockIdx.x & 7;
    const size_t base = (size_t)b * 264 * 384;
    const int t = threadIdx.x;
    const int wave = t >> 6, lane = t & 63;
    const int quad = lane >> 4, l16 = lane & 15;
    const int hq = h * 16;

    for (int i = t; i < 264 * 2; i += 256) {
        int key = i >> 1, dq = (i & 1) * 8;
        *(uint4*)&Ks[key * KLD + dq] =
            *(const uint4*)&qkv[base + (size_t)key * 384 + 128 + hq + dq];
    }
    for (int i = t; i < 264 * 16; i += 256) {
        int s = i >> 4, d = i & 15;
        VT[d * STR + s] = qkv[base + (size_t)s * 384 + 256 + hq + d];
    }
    for (int i = t; i < 16 * 32; i += 256) {
        int d = i >> 5, c = 264 + (i & 31);
        VT[d * STR + c] = 0;
    }
    __syncthreads();

    for (int qt = wave; qt < 17; qt += 4) {
        const int q0 = qt * 16;
        s16x8 qf = (s16x8){0, 0, 0, 0, 0, 0, 0, 0};
        {
            int qrow = q0 + l16;
            if (quad < 2 && qrow < 264)
                qf = *(const s16x8*)&qkv[base + (size_t)qrow * 384 + hq + quad * 8];
        }
        f32x4 sc[17];
        #pragma unroll
        for (int kt = 0; kt < 17; ++kt) {
            s16x8 kf = (s16x8){0, 0, 0, 0, 0, 0, 0, 0};
            if (quad < 2)
                kf = *(const s16x8*)&Ks[(kt * 16 + l16) * KLD + quad * 8];
            f32x4 z = (f32x4){0.f, 0.f, 0.f, 0.f};
            sc[kt] = mfma16(kf, qf, z);
        }
        // softmax in log2 domain (Q pre-scaled); key = kt*16 + quad*4 + r
        float mx = -1e30f;
        #pragma unroll
        for (int kt = 0; kt < 17; ++kt) {
            #pragma unroll
            for (int r = 0; r < 4; ++r) {
                float s = sc[kt][r];
                if (kt == 16 && quad >= 2) s = -1e30f;   // keys >= 264
                sc[kt][r] = s;
                mx = fmaxf(mx, s);
            }
        }
        mx = fmaxf(mx, __shfl_xor(mx, 16, 64));
        mx = fmaxf(mx, __shfl_xor(mx, 32, 64));
        float ls = 0.f;
        #pragma unroll
        for (int kt = 0; kt < 17; ++kt) {
            #pragma unroll
            for (int r = 0; r < 4; ++r) {
                float e = __builtin_amdgcn_exp2f(sc[kt][r] - mx);
                sc[kt][r] = e;
                ls += e;
            }
        }
        ls += __shfl_xor(ls, 16, 64);
        ls += __shfl_xor(ls, 32, 64);
        float rinv = 1.f / ls;
        float rinvT[4];
        #pragma unroll
        for (int r = 0; r < 4; ++r) rinvT[r] = __shfl(rinv, quad * 4 + r, 64);

        // PV: P packed from sc regs via v_perm hi16 truncation
        f32x4 oa = (f32x4){0.f, 0.f, 0.f, 0.f};
        #pragma unroll
        for (int c = 0; c < 9; ++c) {
            const int kt0 = 2 * c, kt1 = 2 * c + 1;
            union { s16x8 v; uint4 w; } pk;
            pk.w.x = __builtin_amdgcn_perm(fbits(sc[kt0][1]), fbits(sc[kt0][0]), 0x07060302u);
            pk.w.y = __builtin_amdgcn_perm(fbits(sc[kt0][3]), fbits(sc[kt0][2]), 0x07060302u);
            if (c == 8) { pk.w.z = 0; pk.w.w = 0; }
            else {
                pk.w.z = __builtin_amdgcn_perm(fbits(sc[kt1][1]), fbits(sc[kt1][0]), 0x07060302u);
                pk.w.w = __builtin_amdgcn_perm(fbits(sc[kt1][3]), fbits(sc[kt1][2]), 0x07060302u);
            }
            union { s16x8 v; uint2 h2[2]; } vt;
            vt.h2[0] = *(const uint2*)&VT[l16 * STR + kt0 * 16 + quad * 4];
            vt.h2[1] = *(const uint2*)&VT[l16 * STR + kt1 * 16 + quad * 4];
            oa = mfma16(pk.v, vt.v, oa);
        }
        #pragma unroll
        for (int r = 0; r < 4; ++r) {
            int row = q0 + quad * 4 + r;
            if (row < 264)
                ctx[((size_t)b * 264 + row) * 128 + hq + l16] = f2bf(oa[r] * rinvT[r]);
        }
    }
}

// ---------------------------------------------------------------------------
extern "C" void kernel_launch(void* const* d_in, const int* in_sizes, int n_in,
                              void* d_out, int out_size, void* d_ws, size_t ws_size,
                              hipStream_t stream)
{
    (void)in_sizes; (void)n_in; (void)out_size; (void)ws_size;
    const float* x    = (const float*)d_in[0];
    const int*   tidx = (const int*)d_in[1];
    const int*   sidx = (const int*)d_in[2];
    const float* cw   = (const float*)d_in[3];
    const float* cb   = (const float*)d_in[4];
    const float* pos  = (const float*)d_in[5];
    const float* ttab = (const float*)d_in[6];
    const float* stab = (const float*)d_in[7];
    const float* cls  = (const float*)d_in[8];
    const float* Wqkv = (const float*)d_in[9];
    const float* bqkv = (const float*)d_in[10];
    const float* Wo   = (const float*)d_in[11];
    const float* bo   = (const float*)d_in[12];
    const float* W1   = (const float*)d_in[13];
    const float* b1   = (const float*)d_in[14];
    const float* W2   = (const float*)d_in[15];
    const float* b2   = (const float*)d_in[16];
    const float* g1   = (const float*)d_in[17];
    const float* be1  = (const float*)d_in[18];
    const float* g2   = (const float*)d_in[19];
    const float* be2  = (const float*)d_in[20];

    char* ws = (char*)d_ws;
    float* h32 = (float*)ws;
    u16* h16    = (u16*)(ws + 17301504);
    u16* big    = (u16*)(ws + 25952256);
    u16* ctx    = (u16*)(ws + 51904512);
    u16* wqkv16 = (u16*)(ws + 60555264);
    u16* wo16   = (u16*)(ws + 61734912);
    u16* w116   = (u16*)(ws + 62128128);
    u16* w216   = (u16*)(ws + 63700992);
    u16* x16    = big;                    // [32256, 96] bf16, free before layer 0
    u16* cw16   = ctx;                    // [128, 96]  bf16, free before layer 0

    cvt_kernel<<<512, 256, 0, stream>>>(Wqkv, wqkv16, 12 * 384 * 128);
    cvt_kernel<<<256, 256, 0, stream>>>(Wo,   wo16,   12 * 128 * 128);
    cvt_kernel<<<512, 256, 0, stream>>>(W1,   w116,   12 * 512 * 128);
    cvt_kernel<<<512, 256, 0, stream>>>(W2,   w216,   12 * 128 * 512);
    cvt_kernel<<<1024, 256, 0, stream>>>(x,   x16,    128 * 252 * 96);
    cvt_kernel<<<48, 256, 0, stream>>>(cw,    cw16,   128 * 96);
    embed_cls_kernel<<<768, 256, 0, stream>>>(cls, pos, h32, h16);
    embed_mfma<<<504, 256, 0, stream>>>(x16, cw16, cb, pos, ttab, stab, tidx, sidx, h32, h16);

    for (int l = 0; l < 12; ++l) {
        gemm_bias<false, true><<<dim3(528, 6), 256, 0, stream>>>(
            h16, wqkv16 + l * 384 * 128, bqkv + l * 384, big, 384, 128);
        attn_kernel<<<1024, 256, 0, stream>>>(big, ctx);
        gemm_ln<128><<<528, 256, 0, stream>>>(
            ctx, wo16 + l * 128 * 128, bo + l * 128, h32, g1 + l * 128, be1 + l * 128, h32, h16);
        gemm_bias<true, false><<<dim3(528, 8), 256, 0, stream>>>(
            h16, w116 + l * 512 * 128, b1 + l * 512, big, 512, 128);
        float* o32 = (l == 11) ? (float*)d_out : h32;
        gemm_ln<512><<<528, 256, 0, stream>>>(
            big, w216 + l * 128 * 512, b2 + l * 128, h32, g2 + l * 128, be2 + l * 128, o32, h16);
    }
}

// Round 8
// 1192.363 us; speedup vs baseline: 1.2024x; 1.0746x over previous
//
#include <hip/hip_runtime.h>

typedef unsigned short u16;
typedef __attribute__((ext_vector_type(8))) short s16x8;
typedef __attribute__((ext_vector_type(4))) float f32x4;

__device__ __forceinline__ float bf2f(u16 u) {
    union { unsigned i; float f; } v; v.i = (unsigned)u << 16; return v.f;
}
__device__ __forceinline__ u16 f2bf(float f) {
    union { float f; unsigned i; } v; v.f = f;
    unsigned r = v.i + 0x7fffu + ((v.i >> 16) & 1u);
    return (u16)(r >> 16);
}
__device__ __forceinline__ unsigned fbits(float f) {
    union { float f; unsigned i; } v; v.f = f; return v.i;
}
__device__ __forceinline__ f32x4 mfma16(s16x8 a, s16x8 b, f32x4 c) {
    return __builtin_amdgcn_mfma_f32_16x16x32_bf16(a, b, c, 0, 0, 0);
}

// ---------------------------------------------------------------------------
// fp32 -> bf16 conversion
// ---------------------------------------------------------------------------
__global__ __launch_bounds__(256)
void cvt_kernel(const float* __restrict__ src, u16* __restrict__ dst, int n)
{
    for (int i = blockIdx.x * 256 + threadIdx.x; i < n; i += gridDim.x * 256)
        dst[i] = f2bf(src[i]);
}

// ---------------------------------------------------------------------------
// cls rows: h[b, s<12, :] = cls[s] + pos[s]   (bf16 out only)
// ---------------------------------------------------------------------------
__global__ __launch_bounds__(256)
void embed_cls_kernel(const float* __restrict__ cls, const float* __restrict__ pos,
                      u16* __restrict__ h16)
{
    int i = blockIdx.x * 256 + threadIdx.x;           // < 128*12*128
    int e = i & 127, s = (i >> 7) % 12, b = i / (12 * 128);
    float v = cls[s * 128 + e] + pos[s * 128 + e];
    h16[((size_t)b * 264 + s) * 128 + e] = f2bf(v);
}

// ---------------------------------------------------------------------------
// Conv-embed via MFMA: rows = (b,l) flat [32256], K=96, N=128. bf16 out only.
// ---------------------------------------------------------------------------
__global__ __launch_bounds__(256)
void embed_mfma(const u16* __restrict__ x16, const u16* __restrict__ cw16,
                const float* __restrict__ cb, const float* __restrict__ pos,
                const float* __restrict__ ttab, const float* __restrict__ stab,
                const int* __restrict__ tidx, const int* __restrict__ sidx,
                u16* __restrict__ h16)
{
    const int t = threadIdx.x;
    const int wave = t >> 6, lane = t & 63;
    const int quad = lane >> 4, l16 = lane & 15;
    const int n0 = wave * 32;

    s16x8 wf[2][3];
    float bv[2];
    #pragma unroll
    for (int nt = 0; nt < 2; ++nt) {
        bv[nt] = cb[n0 + nt * 16 + l16];
        #pragma unroll
        for (int ks = 0; ks < 3; ++ks)
            wf[nt][ks] = *(const s16x8*)&cw16[(n0 + nt * 16 + l16) * 96 + ks * 32 + quad * 8];
    }
    #pragma unroll
    for (int tt = 0; tt < 4; ++tt) {
        const int m0 = (blockIdx.x * 4 + tt) * 16;
        s16x8 af[3];
        #pragma unroll
        for (int ks = 0; ks < 3; ++ks)
            af[ks] = *(const s16x8*)&x16[(size_t)(m0 + l16) * 96 + ks * 32 + quad * 8];
        f32x4 a0 = (f32x4){0.f,0.f,0.f,0.f}, a1 = (f32x4){0.f,0.f,0.f,0.f};
        #pragma unroll
        for (int ks = 0; ks < 3; ++ks) {
            a0 = mfma16(af[ks], wf[0][ks], a0);
            a1 = mfma16(af[ks], wf[1][ks], a1);
        }
        #pragma unroll
        for (int r = 0; r < 4; ++r) {
            int row = m0 + quad * 4 + r;
            int b = row / 252, l = row - b * 252;
            int ti = tidx[row], si = sidx[row];
            size_t tok = (size_t)b * 264 + 12 + l;
            #pragma unroll
            for (int nt = 0; nt < 2; ++nt) {
                int col = n0 + nt * 16 + l16;
                float v = (nt ? a1[r] : a0[r]) + bv[nt]
                        + pos[(12 + l) * 128 + col]
                        + ttab[ti * 128 + col] + stab[si * 128 + col];
                h16[tok * 128 + col] = f2bf(v);
            }
        }
    }
}

// ---------------------------------------------------------------------------
// C[M,N] = act(A[M,K] @ W[N,K]^T + bias). 64x64 block tile, 4 waves, LDK=136.
// QSCALE: multiply output by 0.25*log2(e) when blockIdx.y < 2 (Q cols of qkv).
// ---------------------------------------------------------------------------
template<bool RELU, bool QSCALE>
__global__ __launch_bounds__(256)
void gemm_bias(const u16* __restrict__ A, const u16* __restrict__ W,
               const float* __restrict__ bias, u16* __restrict__ C,
               int N, int K)
{
    const int LDK = 136;
    __shared__ alignas(16) u16 As[64 * 136];
    __shared__ alignas(16) u16 Ws[64 * 136];
    const int m0 = blockIdx.x * 64;
    const int n0 = blockIdx.y * 64;
    const int t = threadIdx.x;
    const int wave = t >> 6, lane = t & 63;
    const int quad = lane >> 4, l16 = lane & 15;
    const int wm = (wave & 1) * 32, wn = (wave >> 1) * 32;

    f32x4 acc[2][2];
    #pragma unroll
    for (int i = 0; i < 2; ++i)
        #pragma unroll
        for (int j = 0; j < 2; ++j) acc[i][j] = (f32x4){0.f, 0.f, 0.f, 0.f};

    for (int kc = 0; kc < K; kc += 128) {
        __syncthreads();
        #pragma unroll
        for (int i = 0; i < 4; ++i) {
            int id = i * 256 + t;
            int row = id >> 4, c8 = (id & 15) << 3;
            *(uint4*)&As[row * LDK + c8] = *(const uint4*)&A[(size_t)(m0 + row) * K + kc + c8];
            *(uint4*)&Ws[row * LDK + c8] = *(const uint4*)&W[(size_t)(n0 + row) * K + kc + c8];
        }
        __syncthreads();
        #pragma unroll
        for (int ks = 0; ks < 4; ++ks) {
            s16x8 a0 = *(const s16x8*)&As[(wm + l16) * LDK + ks * 32 + quad * 8];
            s16x8 a1 = *(const s16x8*)&As[(wm + 16 + l16) * LDK + ks * 32 + quad * 8];
            s16x8 b0 = *(const s16x8*)&Ws[(wn + l16) * LDK + ks * 32 + quad * 8];
            s16x8 b1 = *(const s16x8*)&Ws[(wn + 16 + l16) * LDK + ks * 32 + quad * 8];
            acc[0][0] = mfma16(a0, b0, acc[0][0]);
            acc[0][1] = mfma16(a0, b1, acc[0][1]);
            acc[1][0] = mfma16(a1, b0, acc[1][0]);
            acc[1][1] = mfma16(a1, b1, acc[1][1]);
        }
    }
    #pragma unroll
    for (int ni = 0; ni < 2; ++ni) {
        int col = n0 + wn + ni * 16 + l16;
        float bv = bias[col];
        #pragma unroll
        for (int mi = 0; mi < 2; ++mi) {
            #pragma unroll
            for (int r = 0; r < 4; ++r) {
                int row = m0 + wm + mi * 16 + quad * 4 + r;
                float v = acc[mi][ni][r] + bv;
                if (RELU) v = fmaxf(v, 0.f);
                if (QSCALE && blockIdx.y < 2) v *= 0.360673760222241f; // 0.25*log2(e)
                C[(size_t)row * N + col] = f2bf(v);
            }
        }
    }
}

// ---------------------------------------------------------------------------
// Fused: y = LN(A[M,K] @ W[128,K]^T + bias + resid). 64-row block, 4 waves;
// wave owns 16 full rows -> in-wave LN. Residual is bf16 (h16). Writes bf16,
// or fp32 (final layer) per W32 flag.
// ---------------------------------------------------------------------------
template<int K, bool W32>
__global__ __launch_bounds__(256)
void gemm_ln(const u16* __restrict__ A, const u16* __restrict__ W,
             const float* __restrict__ bias, const u16* __restrict__ resid,
             const float* __restrict__ g, const float* __restrict__ be,
             float* o32, u16* o16)
{
    const int LDK = 136;
    __shared__ alignas(16) u16 As[64 * 136];
    __shared__ alignas(16) u16 Ws[128 * 136];
    const int m0 = blockIdx.x * 64;
    const int t = threadIdx.x;
    const int wave = t >> 6, lane = t & 63;
    const int quad = lane >> 4, l16 = lane & 15;
    const int wr = wave * 16;

    f32x4 acc[8];
    #pragma unroll
    for (int i = 0; i < 8; ++i) acc[i] = (f32x4){0.f, 0.f, 0.f, 0.f};

    for (int kc = 0; kc < K; kc += 128) {
        __syncthreads();
        #pragma unroll
        for (int i = 0; i < 4; ++i) {
            int id = i * 256 + t;
            int row = id >> 4, c8 = (id & 15) << 3;
            *(uint4*)&As[row * LDK + c8] = *(const uint4*)&A[(size_t)(m0 + row) * K + kc + c8];
        }
        #pragma unroll
        for (int i = 0; i < 8; ++i) {
            int id = i * 256 + t;
            int row = id >> 4, c8 = (id & 15) << 3;
            *(uint4*)&Ws[row * LDK + c8] = *(const uint4*)&W[(size_t)row * K + kc + c8];
        }
        __syncthreads();
        #pragma unroll
        for (int ks = 0; ks < 4; ++ks) {
            s16x8 a = *(const s16x8*)&As[(wr + l16) * LDK + ks * 32 + quad * 8];
            #pragma unroll
            for (int nt = 0; nt < 8; ++nt) {
                s16x8 b = *(const s16x8*)&Ws[(nt * 16 + l16) * LDK + ks * 32 + quad * 8];
                acc[nt] = mfma16(a, b, acc[nt]);
            }
        }
    }
    #pragma unroll
    for (int nt = 0; nt < 8; ++nt) {
        int col = nt * 16 + l16;
        float bv = bias[col];
        #pragma unroll
        for (int r = 0; r < 4; ++r) {
            int row = m0 + wr + quad * 4 + r;
            acc[nt][r] += bv + bf2f(resid[(size_t)row * 128 + col]);
        }
    }
    float sm[4], sq[4];
    #pragma unroll
    for (int r = 0; r < 4; ++r) {
        float s = 0.f, q = 0.f;
        #pragma unroll
        for (int nt = 0; nt < 8; ++nt) { float v = acc[nt][r]; s += v; q += v * v; }
        sm[r] = s; sq[r] = q;
    }
    #pragma unroll
    for (int mk = 1; mk < 16; mk <<= 1) {
        #pragma unroll
        for (int r = 0; r < 4; ++r) {
            sm[r] += __shfl_xor(sm[r], mk, 64);
            sq[r] += __shfl_xor(sq[r], mk, 64);
        }
    }
    #pragma unroll
    for (int r = 0; r < 4; ++r) {
        float mean = sm[r] * (1.f / 128.f);
        float var = sq[r] * (1.f / 128.f) - mean * mean;
        float rstd = rsqrtf(var + 1e-5f);
        int row = m0 + wr + quad * 4 + r;
        #pragma unroll
        for (int nt = 0; nt < 8; ++nt) {
            int col = nt * 16 + l16;
            float y = (acc[nt][r] - mean) * rstd * g[col] + be[col];
            if (W32) o32[(size_t)row * 128 + col] = y;
            else     o16[(size_t)row * 128 + col] = f2bf(y);
        }
    }
}

// ---------------------------------------------------------------------------
// Attention v3: transpose-free + VALU diet. Q pre-scaled by 0.25*log2(e) in
// the qkv GEMM, exp via raw v_exp_f32 (exp2), P packed by v_perm truncation,
// 1/l normalization deferred to the 4-element output.
// ---------------------------------------------------------------------------
__global__ __launch_bounds__(256)
void attn_kernel(const u16* __restrict__ qkv, u16* __restrict__ ctx)
{
    const int STR = 296;  // VT: [d=16][key padded], keys 264..295 zeroed
    const int KLD = 24;   // Ks: [key=272][d=16 pad 24]
    __shared__ alignas(16) u16 VT[16 * STR];
    __shared__ alignas(16) u16 Ks[272 * KLD];
    const int b = blockIdx.x >> 3, h = blockIdx.x & 7;
    const size_t base = (size_t)b * 264 * 384;
    const int t = threadIdx.x;
    const int wave = t >> 6, lane = t & 63;
    const int quad = lane >> 4, l16 = lane & 15;
    const int hq = h * 16;

    for (int i = t; i < 264 * 2; i += 256) {
        int key = i >> 1, dq = (i & 1) * 8;
        *(uint4*)&Ks[key * KLD + dq] =
            *(const uint4*)&qkv[base + (size_t)key * 384 + 128 + hq + dq];
    }
    for (int i = t; i < 264 * 16; i += 256) {
        int s = i >> 4, d = i & 15;
        VT[d * STR + s] = qkv[base + (size_t)s * 384 + 256 + hq + d];
    }
    for (int i = t; i < 16 * 32; i += 256) {
        int d = i >> 5, c = 264 + (i & 31);
        VT[d * STR + c] = 0;
    }
    __syncthreads();

    for (int qt = wave; qt < 17; qt += 4) {
        const int q0 = qt * 16;
        s16x8 qf = (s16x8){0, 0, 0, 0, 0, 0, 0, 0};
        {
            int qrow = q0 + l16;
            if (quad < 2 && qrow < 264)
                qf = *(const s16x8*)&qkv[base + (size_t)qrow * 384 + hq + quad * 8];
        }
        f32x4 sc[17];
        #pragma unroll
        for (int kt = 0; kt < 17; ++kt) {
            s16x8 kf = (s16x8){0, 0, 0, 0, 0, 0, 0, 0};
            if (quad < 2)
                kf = *(const s16x8*)&Ks[(kt * 16 + l16) * KLD + quad * 8];
            f32x4 z = (f32x4){0.f, 0.f, 0.f, 0.f};
            sc[kt] = mfma16(kf, qf, z);
        }
        // softmax in log2 domain (Q pre-scaled); key = kt*16 + quad*4 + r
        float mx = -1e30f;
        #pragma unroll
        for (int kt = 0; kt < 17; ++kt) {
            #pragma unroll
            for (int r = 0; r < 4; ++r) {
                float s = sc[kt][r];
                if (kt == 16 && quad >= 2) s = -1e30f;   // keys >= 264
                sc[kt][r] = s;
                mx = fmaxf(mx, s);
            }
        }
        mx = fmaxf(mx, __shfl_xor(mx, 16, 64));
        mx = fmaxf(mx, __shfl_xor(mx, 32, 64));
        float ls = 0.f;
        #pragma unroll
        for (int kt = 0; kt < 17; ++kt) {
            #pragma unroll
            for (int r = 0; r < 4; ++r) {
                float e = __builtin_amdgcn_exp2f(sc[kt][r] - mx);
                sc[kt][r] = e;
                ls += e;
            }
        }
        ls += __shfl_xor(ls, 16, 64);
        ls += __shfl_xor(ls, 32, 64);
        float rinv = 1.f / ls;
        float rinvT[4];
        #pragma unroll
        for (int r = 0; r < 4; ++r) rinvT[r] = __shfl(rinv, quad * 4 + r, 64);

        // PV: P packed from sc regs via v_perm hi16 truncation
        f32x4 oa = (f32x4){0.f, 0.f, 0.f, 0.f};
        #pragma unroll
        for (int c = 0; c < 9; ++c) {
            const int kt0 = 2 * c, kt1 = 2 * c + 1;
            union { s16x8 v; uint4 w; } pk;
            pk.w.x = __builtin_amdgcn_perm(fbits(sc[kt0][1]), fbits(sc[kt0][0]), 0x07060302u);
            pk.w.y = __builtin_amdgcn_perm(fbits(sc[kt0][3]), fbits(sc[kt0][2]), 0x07060302u);
            if (c == 8) { pk.w.z = 0; pk.w.w = 0; }
            else {
                pk.w.z = __builtin_amdgcn_perm(fbits(sc[kt1][1]), fbits(sc[kt1][0]), 0x07060302u);
                pk.w.w = __builtin_amdgcn_perm(fbits(sc[kt1][3]), fbits(sc[kt1][2]), 0x07060302u);
            }
            union { s16x8 v; uint2 h2[2]; } vt;
            vt.h2[0] = *(const uint2*)&VT[l16 * STR + kt0 * 16 + quad * 4];
            vt.h2[1] = *(const uint2*)&VT[l16 * STR + kt1 * 16 + quad * 4];
            oa = mfma16(pk.v, vt.v, oa);
        }
        #pragma unroll
        for (int r = 0; r < 4; ++r) {
            int row = q0 + quad * 4 + r;
            if (row < 264)
                ctx[((size_t)b * 264 + row) * 128 + hq + l16] = f2bf(oa[r] * rinvT[r]);
        }
    }
}

// ---------------------------------------------------------------------------
extern "C" void kernel_launch(void* const* d_in, const int* in_sizes, int n_in,
                              void* d_out, int out_size, void* d_ws, size_t ws_size,
                              hipStream_t stream)
{
    (void)in_sizes; (void)n_in; (void)out_size; (void)ws_size;
    const float* x    = (const float*)d_in[0];
    const int*   tidx = (const int*)d_in[1];
    const int*   sidx = (const int*)d_in[2];
    const float* cw   = (const float*)d_in[3];
    const float* cb   = (const float*)d_in[4];
    const float* pos  = (const float*)d_in[5];
    const float* ttab = (const float*)d_in[6];
    const float* stab = (const float*)d_in[7];
    const float* cls  = (const float*)d_in[8];
    const float* Wqkv = (const float*)d_in[9];
    const float* bqkv = (const float*)d_in[10];
    const float* Wo   = (const float*)d_in[11];
    const float* bo   = (const float*)d_in[12];
    const float* W1   = (const float*)d_in[13];
    const float* b1   = (const float*)d_in[14];
    const float* W2   = (const float*)d_in[15];
    const float* b2   = (const float*)d_in[16];
    const float* g1   = (const float*)d_in[17];
    const float* be1  = (const float*)d_in[18];
    const float* g2   = (const float*)d_in[19];
    const float* be2  = (const float*)d_in[20];

    // workspace layout (bytes):
    //   h16  [33792,128] bf16 @ 0          ( 8650752)
    //   hA   [33792,128] bf16 @ 8650752    ( 8650752)  LN1 out
    //   big  [33792,512] bf16 @ 17301504   (34603008)  qkv(384)/ff1(512); x16 alias
    //   ctx  @ 51904512 (8650752); cw16 alias pre-layer0
    //   bf16 weights @ 60555264: wqkv 1179648 | wo 393216 | w1 1572864 | w2 1572864
    char* ws = (char*)d_ws;
    u16* h16    = (u16*)ws;
    u16* hA     = (u16*)(ws + 8650752);
    u16* big    = (u16*)(ws + 17301504);
    u16* ctx    = (u16*)(ws + 51904512);
    u16* wqkv16 = (u16*)(ws + 60555264);
    u16* wo16   = (u16*)(ws + 61734912);
    u16* w116   = (u16*)(ws + 62128128);
    u16* w216   = (u16*)(ws + 63700992);
    u16* x16    = big;                    // [32256, 96] bf16, free before layer 0
    u16* cw16   = ctx;                    // [128, 96]  bf16, free before layer 0

    cvt_kernel<<<512, 256, 0, stream>>>(Wqkv, wqkv16, 12 * 384 * 128);
    cvt_kernel<<<256, 256, 0, stream>>>(Wo,   wo16,   12 * 128 * 128);
    cvt_kernel<<<512, 256, 0, stream>>>(W1,   w116,   12 * 512 * 128);
    cvt_kernel<<<512, 256, 0, stream>>>(W2,   w216,   12 * 128 * 512);
    cvt_kernel<<<1024, 256, 0, stream>>>(x,   x16,    128 * 252 * 96);
    cvt_kernel<<<48, 256, 0, stream>>>(cw,    cw16,   128 * 96);
    embed_cls_kernel<<<768, 256, 0, stream>>>(cls, pos, h16);
    embed_mfma<<<504, 256, 0, stream>>>(x16, cw16, cb, pos, ttab, stab, tidx, sidx, h16);

    for (int l = 0; l < 12; ++l) {
        gemm_bias<false, true><<<dim3(528, 6), 256, 0, stream>>>(
            h16, wqkv16 + l * 384 * 128, bqkv + l * 384, big, 384, 128);
        attn_kernel<<<1024, 256, 0, stream>>>(big, ctx);
        gemm_ln<128, false><<<528, 256, 0, stream>>>(
            ctx, wo16 + l * 128 * 128, bo + l * 128, h16, g1 + l * 128, be1 + l * 128,
            nullptr, hA);
        gemm_bias<true, false><<<dim3(528, 8), 256, 0, stream>>>(
            hA, w116 + l * 512 * 128, b1 + l * 512, big, 512, 128);
        if (l == 11) {
            gemm_ln<512, true><<<528, 256, 0, stream>>>(
                big, w216 + l * 128 * 512, b2 + l * 128, hA, g2 + l * 128, be2 + l * 128,
                (float*)d_out, nullptr);
        } else {
            gemm_ln<512, false><<<528, 256, 0, stream>>>(
                big, w216 + l * 128 * 512, b2 + l * 128, hA, g2 + l * 128, be2 + l * 128,
                nullptr, h16);
        }
    }
}

// Round 9
// 1175.200 us; speedup vs baseline: 1.2200x; 1.0146x over previous
//
#include <hip/hip_runtime.h>

typedef unsigned short u16;
typedef __attribute__((ext_vector_type(8))) short s16x8;
typedef __attribute__((ext_vector_type(4))) float f32x4;

__device__ __forceinline__ float bf2f(u16 u) {
    union { unsigned i; float f; } v; v.i = (unsigned)u << 16; return v.f;
}
__device__ __forceinline__ u16 f2bf(float f) {
    union { float f; unsigned i; } v; v.f = f;
    unsigned r = v.i + 0x7fffu + ((v.i >> 16) & 1u);
    return (u16)(r >> 16);
}
__device__ __forceinline__ unsigned fbits(float f) {
    union { float f; unsigned i; } v; v.f = f; return v.i;
}
__device__ __forceinline__ f32x4 mfma16(s16x8 a, s16x8 b, f32x4 c) {
    return __builtin_amdgcn_mfma_f32_16x16x32_bf16(a, b, c, 0, 0, 0);
}

#define PLANE 4325376   // u16 elements per qkv plane: 128*8*264*16

// ---------------------------------------------------------------------------
// fp32 -> bf16 conversion
// ---------------------------------------------------------------------------
__global__ __launch_bounds__(256)
void cvt_kernel(const float* __restrict__ src, u16* __restrict__ dst, int n)
{
    for (int i = blockIdx.x * 256 + threadIdx.x; i < n; i += gridDim.x * 256)
        dst[i] = f2bf(src[i]);
}

// ---------------------------------------------------------------------------
// cls rows: h[b, s<12, :] = cls[s] + pos[s]   (bf16 out only)
// ---------------------------------------------------------------------------
__global__ __launch_bounds__(256)
void embed_cls_kernel(const float* __restrict__ cls, const float* __restrict__ pos,
                      u16* __restrict__ h16)
{
    int i = blockIdx.x * 256 + threadIdx.x;           // < 128*12*128
    int e = i & 127, s = (i >> 7) % 12, b = i / (12 * 128);
    float v = cls[s * 128 + e] + pos[s * 128 + e];
    h16[((size_t)b * 264 + s) * 128 + e] = f2bf(v);
}

// ---------------------------------------------------------------------------
// Conv-embed via MFMA: rows = (b,l) flat [32256], K=96, N=128. bf16 out only.
// ---------------------------------------------------------------------------
__global__ __launch_bounds__(256)
void embed_mfma(const u16* __restrict__ x16, const u16* __restrict__ cw16,
                const float* __restrict__ cb, const float* __restrict__ pos,
                const float* __restrict__ ttab, const float* __restrict__ stab,
                const int* __restrict__ tidx, const int* __restrict__ sidx,
                u16* __restrict__ h16)
{
    const int t = threadIdx.x;
    const int wave = t >> 6, lane = t & 63;
    const int quad = lane >> 4, l16 = lane & 15;
    const int n0 = wave * 32;

    s16x8 wf[2][3];
    float bv[2];
    #pragma unroll
    for (int nt = 0; nt < 2; ++nt) {
        bv[nt] = cb[n0 + nt * 16 + l16];
        #pragma unroll
        for (int ks = 0; ks < 3; ++ks)
            wf[nt][ks] = *(const s16x8*)&cw16[(n0 + nt * 16 + l16) * 96 + ks * 32 + quad * 8];
    }
    #pragma unroll
    for (int tt = 0; tt < 4; ++tt) {
        const int m0 = (blockIdx.x * 4 + tt) * 16;
        s16x8 af[3];
        #pragma unroll
        for (int ks = 0; ks < 3; ++ks)
            af[ks] = *(const s16x8*)&x16[(size_t)(m0 + l16) * 96 + ks * 32 + quad * 8];
        f32x4 a0 = (f32x4){0.f,0.f,0.f,0.f}, a1 = (f32x4){0.f,0.f,0.f,0.f};
        #pragma unroll
        for (int ks = 0; ks < 3; ++ks) {
            a0 = mfma16(af[ks], wf[0][ks], a0);
            a1 = mfma16(af[ks], wf[1][ks], a1);
        }
        #pragma unroll
        for (int r = 0; r < 4; ++r) {
            int row = m0 + quad * 4 + r;
            int b = row / 252, l = row - b * 252;
            int ti = tidx[row], si = sidx[row];
            size_t tok = (size_t)b * 264 + 12 + l;
            #pragma unroll
            for (int nt = 0; nt < 2; ++nt) {
                int col = n0 + nt * 16 + l16;
                float v = (nt ? a1[r] : a0[r]) + bv[nt]
                        + pos[(12 + l) * 128 + col]
                        + ttab[ti * 128 + col] + stab[si * 128 + col];
                h16[tok * 128 + col] = f2bf(v);
            }
        }
    }
}

// ---------------------------------------------------------------------------
// C = act(A[M,K] @ W[N,K]^T + bias). 64x64 block tile, 4 waves, LDK=136.
// QSCALE: multiply by 0.25*log2(e) when blockIdx.y < 2 (Q cols of qkv).
// QKVL: scatter stores to head-blocked planes Q|K|V [B][H][S][16].
// ---------------------------------------------------------------------------
template<bool RELU, bool QSCALE, bool QKVL>
__global__ __launch_bounds__(256)
void gemm_bias(const u16* __restrict__ A, const u16* __restrict__ W,
               const float* __restrict__ bias, u16* __restrict__ C,
               int N, int K)
{
    const int LDK = 136;
    __shared__ alignas(16) u16 As[64 * 136];
    __shared__ alignas(16) u16 Ws[64 * 136];
    const int m0 = blockIdx.x * 64;
    const int n0 = blockIdx.y * 64;
    const int t = threadIdx.x;
    const int wave = t >> 6, lane = t & 63;
    const int quad = lane >> 4, l16 = lane & 15;
    const int wm = (wave & 1) * 32, wn = (wave >> 1) * 32;

    f32x4 acc[2][2];
    #pragma unroll
    for (int i = 0; i < 2; ++i)
        #pragma unroll
        for (int j = 0; j < 2; ++j) acc[i][j] = (f32x4){0.f, 0.f, 0.f, 0.f};

    for (int kc = 0; kc < K; kc += 128) {
        __syncthreads();
        #pragma unroll
        for (int i = 0; i < 4; ++i) {
            int id = i * 256 + t;
            int row = id >> 4, c8 = (id & 15) << 3;
            *(uint4*)&As[row * LDK + c8] = *(const uint4*)&A[(size_t)(m0 + row) * K + kc + c8];
            *(uint4*)&Ws[row * LDK + c8] = *(const uint4*)&W[(size_t)(n0 + row) * K + kc + c8];
        }
        __syncthreads();
        #pragma unroll
        for (int ks = 0; ks < 4; ++ks) {
            s16x8 a0 = *(const s16x8*)&As[(wm + l16) * LDK + ks * 32 + quad * 8];
            s16x8 a1 = *(const s16x8*)&As[(wm + 16 + l16) * LDK + ks * 32 + quad * 8];
            s16x8 b0 = *(const s16x8*)&Ws[(wn + l16) * LDK + ks * 32 + quad * 8];
            s16x8 b1 = *(const s16x8*)&Ws[(wn + 16 + l16) * LDK + ks * 32 + quad * 8];
            acc[0][0] = mfma16(a0, b0, acc[0][0]);
            acc[0][1] = mfma16(a0, b1, acc[0][1]);
            acc[1][0] = mfma16(a1, b0, acc[1][0]);
            acc[1][1] = mfma16(a1, b1, acc[1][1]);
        }
    }
    #pragma unroll
    for (int ni = 0; ni < 2; ++ni) {
        int col = n0 + wn + ni * 16 + l16;
        float bv = bias[col];
        #pragma unroll
        for (int mi = 0; mi < 2; ++mi) {
            #pragma unroll
            for (int r = 0; r < 4; ++r) {
                int row = m0 + wm + mi * 16 + quad * 4 + r;
                float v = acc[mi][ni][r] + bv;
                if (RELU) v = fmaxf(v, 0.f);
                if (QSCALE && blockIdx.y < 2) v *= 0.360673760222241f; // 0.25*log2(e)
                if (QKVL) {
                    int part = col >> 7, hh = (col >> 4) & 7, d = col & 15;
                    int b = row / 264, s = row - b * 264;
                    C[(size_t)part * PLANE + (size_t)b * 33792 + hh * 4224 + s * 16 + d] = f2bf(v);
                } else {
                    C[(size_t)row * N + col] = f2bf(v);
                }
            }
        }
    }
}

// ---------------------------------------------------------------------------
// Fused: y = LN(A[M,K] @ W[128,K]^T + bias + resid). 64-row block, 4 waves;
// wave owns 16 full rows -> in-wave LN. Residual bf16. W32: fp32 final out.
// ---------------------------------------------------------------------------
template<int K, bool W32>
__global__ __launch_bounds__(256)
void gemm_ln(const u16* __restrict__ A, const u16* __restrict__ W,
             const float* __restrict__ bias, const u16* __restrict__ resid,
             const float* __restrict__ g, const float* __restrict__ be,
             float* o32, u16* o16)
{
    const int LDK = 136;
    __shared__ alignas(16) u16 As[64 * 136];
    __shared__ alignas(16) u16 Ws[128 * 136];
    const int m0 = blockIdx.x * 64;
    const int t = threadIdx.x;
    const int wave = t >> 6, lane = t & 63;
    const int quad = lane >> 4, l16 = lane & 15;
    const int wr = wave * 16;

    f32x4 acc[8];
    #pragma unroll
    for (int i = 0; i < 8; ++i) acc[i] = (f32x4){0.f, 0.f, 0.f, 0.f};

    for (int kc = 0; kc < K; kc += 128) {
        __syncthreads();
        #pragma unroll
        for (int i = 0; i < 4; ++i) {
            int id = i * 256 + t;
            int row = id >> 4, c8 = (id & 15) << 3;
            *(uint4*)&As[row * LDK + c8] = *(const uint4*)&A[(size_t)(m0 + row) * K + kc + c8];
        }
        #pragma unroll
        for (int i = 0; i < 8; ++i) {
            int id = i * 256 + t;
            int row = id >> 4, c8 = (id & 15) << 3;
            *(uint4*)&Ws[row * LDK + c8] = *(const uint4*)&W[(size_t)row * K + kc + c8];
        }
        __syncthreads();
        #pragma unroll
        for (int ks = 0; ks < 4; ++ks) {
            s16x8 a = *(const s16x8*)&As[(wr + l16) * LDK + ks * 32 + quad * 8];
            #pragma unroll
            for (int nt = 0; nt < 8; ++nt) {
                s16x8 b = *(const s16x8*)&Ws[(nt * 16 + l16) * LDK + ks * 32 + quad * 8];
                acc[nt] = mfma16(a, b, acc[nt]);
            }
        }
    }
    #pragma unroll
    for (int nt = 0; nt < 8; ++nt) {
        int col = nt * 16 + l16;
        float bv = bias[col];
        #pragma unroll
        for (int r = 0; r < 4; ++r) {
            int row = m0 + wr + quad * 4 + r;
            acc[nt][r] += bv + bf2f(resid[(size_t)row * 128 + col]);
        }
    }
    float sm[4], sq[4];
    #pragma unroll
    for (int r = 0; r < 4; ++r) {
        float s = 0.f, q = 0.f;
        #pragma unroll
        for (int nt = 0; nt < 8; ++nt) { float v = acc[nt][r]; s += v; q += v * v; }
        sm[r] = s; sq[r] = q;
    }
    #pragma unroll
    for (int mk = 1; mk < 16; mk <<= 1) {
        #pragma unroll
        for (int r = 0; r < 4; ++r) {
            sm[r] += __shfl_xor(sm[r], mk, 64);
            sq[r] += __shfl_xor(sq[r], mk, 64);
        }
    }
    #pragma unroll
    for (int r = 0; r < 4; ++r) {
        float mean = sm[r] * (1.f / 128.f);
        float var = sq[r] * (1.f / 128.f) - mean * mean;
        float rstd = rsqrtf(var + 1e-5f);
        int row = m0 + wr + quad * 4 + r;
        #pragma unroll
        for (int nt = 0; nt < 8; ++nt) {
            int col = nt * 16 + l16;
            float y = (acc[nt][r] - mean) * rstd * g[col] + be[col];
            if (W32) o32[(size_t)row * 128 + col] = y;
            else     o16[(size_t)row * 128 + col] = f2bf(y);
        }
    }
}

// ---------------------------------------------------------------------------
// Attention v4: head-blocked planes. Per (b,h): Q/K/V each 8448 B contiguous.
// K staged via coalesced uint4; V transposed via uint4 regs + scalar LDS
// writes (bank-staggered). Transpose-free scores, exp2 softmax, v_perm P.
// ---------------------------------------------------------------------------
__global__ __launch_bounds__(256)
void attn_kernel(const u16* __restrict__ qkv, u16* __restrict__ ctx)
{
    const int STR = 296;  // VT: [d=16][key padded], keys 264..295 zeroed
    const int KLD = 24;   // Ks: [key=272][d=16 pad 24]
    __shared__ alignas(16) u16 VT[16 * STR];
    __shared__ alignas(16) u16 Ks[272 * KLD];
    const int b = blockIdx.x >> 3, h = blockIdx.x & 7;
    const u16* qp = qkv + (size_t)(b * 8 + h) * 4224;
    const u16* kp = qp + PLANE;
    const u16* vp = qp + 2 * PLANE;
    const int t = threadIdx.x;
    const int wave = t >> 6, lane = t & 63;
    const int quad = lane >> 4, l16 = lane & 15;
    const int hq = h * 16;

    // K: contiguous -> coalesced uint4 into padded LDS rows
    for (int i = t; i < 528; i += 256)
        *(uint4*)&Ks[(i >> 1) * KLD + (i & 1) * 8] = *(const uint4*)&kp[i * 8];
    // V: coalesced uint4 into regs, scalar transpose into VT (stagger halves)
    for (int i = t; i < 528; i += 256) {
        int key = i >> 1, dq = (i & 1) * 8;
        union { uint4 w; u16 u[8]; } vv;
        vv.w = *(const uint4*)&vp[i * 8];
        #pragma unroll
        for (int j = 0; j < 8; ++j) {
            int jj = (i & 1) ? ((j + 4) & 7) : j;
            VT[(dq + jj) * STR + key] = vv.u[jj];
        }
    }
    for (int i = t; i < 16 * 32; i += 256) {
        int d = i >> 5, c = 264 + (i & 31);
        VT[d * STR + c] = 0;
    }
    __syncthreads();

    for (int qt = wave; qt < 17; qt += 4) {
        const int q0 = qt * 16;
        s16x8 qf = (s16x8){0, 0, 0, 0, 0, 0, 0, 0};
        {
            int qrow = q0 + l16;
            if (quad < 2 && qrow < 264)
                qf = *(const s16x8*)&qp[qrow * 16 + quad * 8];
        }
        f32x4 sc[17];
        #pragma unroll
        for (int kt = 0; kt < 17; ++kt) {
            s16x8 kf = (s16x8){0, 0, 0, 0, 0, 0, 0, 0};
            if (quad < 2)
                kf = *(const s16x8*)&Ks[(kt * 16 + l16) * KLD + quad * 8];
            f32x4 z = (f32x4){0.f, 0.f, 0.f, 0.f};
            sc[kt] = mfma16(kf, qf, z);
        }
        // softmax in log2 domain (Q pre-scaled); key = kt*16 + quad*4 + r
        float mx = -1e30f;
        #pragma unroll
        for (int kt = 0; kt < 17; ++kt) {
            #pragma unroll
            for (int r = 0; r < 4; ++r) {
                float s = sc[kt][r];
                if (kt == 16 && quad >= 2) s = -1e30f;   // keys >= 264
                sc[kt][r] = s;
                mx = fmaxf(mx, s);
            }
        }
        mx = fmaxf(mx, __shfl_xor(mx, 16, 64));
        mx = fmaxf(mx, __shfl_xor(mx, 32, 64));
        float ls = 0.f;
        #pragma unroll
        for (int kt = 0; kt < 17; ++kt) {
            #pragma unroll
            for (int r = 0; r < 4; ++r) {
                float e = __builtin_amdgcn_exp2f(sc[kt][r] - mx);
                sc[kt][r] = e;
                ls += e;
            }
        }
        ls += __shfl_xor(ls, 16, 64);
        ls += __shfl_xor(ls, 32, 64);
        float rinv = 1.f / ls;
        float rinvT[4];
        #pragma unroll
        for (int r = 0; r < 4; ++r) rinvT[r] = __shfl(rinv, quad * 4 + r, 64);

        // PV: P packed from sc regs via v_perm hi16 truncation
        f32x4 oa = (f32x4){0.f, 0.f, 0.f, 0.f};
        #pragma unroll
        for (int c = 0; c < 9; ++c) {
            const int kt0 = 2 * c, kt1 = 2 * c + 1;
            union { s16x8 v; uint4 w; } pk;
            pk.w.x = __builtin_amdgcn_perm(fbits(sc[kt0][1]), fbits(sc[kt0][0]), 0x07060302u);
            pk.w.y = __builtin_amdgcn_perm(fbits(sc[kt0][3]), fbits(sc[kt0][2]), 0x07060302u);
            if (c == 8) { pk.w.z = 0; pk.w.w = 0; }
            else {
                pk.w.z = __builtin_amdgcn_perm(fbits(sc[kt1][1]), fbits(sc[kt1][0]), 0x07060302u);
                pk.w.w = __builtin_amdgcn_perm(fbits(sc[kt1][3]), fbits(sc[kt1][2]), 0x07060302u);
            }
            union { s16x8 v; uint2 h2[2]; } vt;
            vt.h2[0] = *(const uint2*)&VT[l16 * STR + kt0 * 16 + quad * 4];
            vt.h2[1] = *(const uint2*)&VT[l16 * STR + kt1 * 16 + quad * 4];
            oa = mfma16(pk.v, vt.v, oa);
        }
        #pragma unroll
        for (int r = 0; r < 4; ++r) {
            int row = q0 + quad * 4 + r;
            if (row < 264)
                ctx[((size_t)b * 264 + row) * 128 + hq + l16] = f2bf(oa[r] * rinvT[r]);
        }
    }
}

// ---------------------------------------------------------------------------
extern "C" void kernel_launch(void* const* d_in, const int* in_sizes, int n_in,
                              void* d_out, int out_size, void* d_ws, size_t ws_size,
                              hipStream_t stream)
{
    (void)in_sizes; (void)n_in; (void)out_size; (void)ws_size;
    const float* x    = (const float*)d_in[0];
    const int*   tidx = (const int*)d_in[1];
    const int*   sidx = (const int*)d_in[2];
    const float* cw   = (const float*)d_in[3];
    const float* cb   = (const float*)d_in[4];
    const float* pos  = (const float*)d_in[5];
    const float* ttab = (const float*)d_in[6];
    const float* stab = (const float*)d_in[7];
    const float* cls  = (const float*)d_in[8];
    const float* Wqkv = (const float*)d_in[9];
    const float* bqkv = (const float*)d_in[10];
    const float* Wo   = (const float*)d_in[11];
    const float* bo   = (const float*)d_in[12];
    const float* W1   = (const float*)d_in[13];
    const float* b1   = (const float*)d_in[14];
    const float* W2   = (const float*)d_in[15];
    const float* b2   = (const float*)d_in[16];
    const float* g1   = (const float*)d_in[17];
    const float* be1  = (const float*)d_in[18];
    const float* g2   = (const float*)d_in[19];
    const float* be2  = (const float*)d_in[20];

    // workspace layout (bytes):
    //   h16  [33792,128] bf16 @ 0          ( 8650752)
    //   hA   [33792,128] bf16 @ 8650752    ( 8650752)  LN1 out
    //   big  @ 17301504 (34603008)  qkv planes (25952256) / ff1 [33792,512]; x16 alias
    //   ctx  @ 51904512 (8650752); cw16 alias pre-layer0
    //   bf16 weights @ 60555264: wqkv 1179648 | wo 393216 | w1 1572864 | w2 1572864
    char* ws = (char*)d_ws;
    u16* h16    = (u16*)ws;
    u16* hA     = (u16*)(ws + 8650752);
    u16* big    = (u16*)(ws + 17301504);
    u16* ctx    = (u16*)(ws + 51904512);
    u16* wqkv16 = (u16*)(ws + 60555264);
    u16* wo16   = (u16*)(ws + 61734912);
    u16* w116   = (u16*)(ws + 62128128);
    u16* w216   = (u16*)(ws + 63700992);
    u16* x16    = big;                    // [32256, 96] bf16, free before layer 0
    u16* cw16   = ctx;                    // [128, 96]  bf16, free before layer 0

    cvt_kernel<<<512, 256, 0, stream>>>(Wqkv, wqkv16, 12 * 384 * 128);
    cvt_kernel<<<256, 256, 0, stream>>>(Wo,   wo16,   12 * 128 * 128);
    cvt_kernel<<<512, 256, 0, stream>>>(W1,   w116,   12 * 512 * 128);
    cvt_kernel<<<512, 256, 0, stream>>>(W2,   w216,   12 * 128 * 512);
    cvt_kernel<<<1024, 256, 0, stream>>>(x,   x16,    128 * 252 * 96);
    cvt_kernel<<<48, 256, 0, stream>>>(cw,    cw16,   128 * 96);
    embed_cls_kernel<<<768, 256, 0, stream>>>(cls, pos, h16);
    embed_mfma<<<504, 256, 0, stream>>>(x16, cw16, cb, pos, ttab, stab, tidx, sidx, h16);

    for (int l = 0; l < 12; ++l) {
        gemm_bias<false, true, true><<<dim3(528, 6), 256, 0, stream>>>(
            h16, wqkv16 + l * 384 * 128, bqkv + l * 384, big, 384, 128);
        attn_kernel<<<1024, 256, 0, stream>>>(big, ctx);
        gemm_ln<128, false><<<528, 256, 0, stream>>>(
            ctx, wo16 + l * 128 * 128, bo + l * 128, h16, g1 + l * 128, be1 + l * 128,
            nullptr, hA);
        gemm_bias<true, false, false><<<dim3(528, 8), 256, 0, stream>>>(
            hA, w116 + l * 512 * 128, b1 + l * 512, big, 512, 128);
        if (l == 11) {
            gemm_ln<512, true><<<528, 256, 0, stream>>>(
                big, w216 + l * 128 * 512, b2 + l * 128, hA, g2 + l * 128, be2 + l * 128,
                (float*)d_out, nullptr);
        } else {
            gemm_ln<512, false><<<528, 256, 0, stream>>>(
                big, w216 + l * 128 * 512, b2 + l * 128, hA, g2 + l * 128, be2 + l * 128,
                nullptr, h16);
        }
    }
}